// Round 3
// baseline (97.519 us; speedup 1.0000x reference)
//
#include <hip/hip_runtime.h>

#define NBINS 15
#define NTHREADS 256
#define NWAVES 4          // 256 / 64
#define NBLOCKS 2048      // ~8 blocks/CU, grid-stride
#define UNROLL 4          // 8 loads in flight per thread

// Streaming pass, pure-register accumulation, logit-domain binning.
// S[k] = sum over elements with p > k/15 of t, where t = p - acc.
// p > k/15  <=>  x > ln(k/(15-k)), so the 15 compares are on x directly
// and don't wait for the sigmoid. Per-bin (conf - acc) = S[b] - S[b+1].
__global__ __launch_bounds__(NTHREADS) void ece_partial_kernel(
    const float* __restrict__ logits,
    const int* __restrict__ labels,
    float* __restrict__ partials,
    int n)
{
    // CE[0]: p>0 fails only when sigmoid underflows (x < -88.72)
    const float CE[NBINS] = { -88.72284f,
        -2.63905733f, -1.87180218f, -1.38629436f, -1.01160091f,
        -0.69314718f, -0.40546511f, -0.13353139f,  0.13353139f,
         0.40546511f,  0.69314718f,  1.01160091f,  1.38629436f,
         1.87180218f,  2.63905733f };

    float S[NBINS];
    #pragma unroll
    for (int k = 0; k < NBINS; ++k) S[k] = 0.0f;

    const int tid  = threadIdx.x;
    const int lane = tid & 63;
    const int w    = tid >> 6;

    const int n4 = n >> 2;
    const float4* L4 = (const float4*)logits;
    const int4*   Y4 = (const int4*)labels;

    const int macroStride = NBLOCKS * NTHREADS * UNROLL;
    const int nMacro = n4 / macroStride;

    int i = blockIdx.x * (NTHREADS * UNROLL) + tid;
    for (int m = 0; m < nMacro; ++m, i += macroStride) {
        // issue all 8 loads before any compute (MLP)
        float4 x[UNROLL];
        int4   y[UNROLL];
        #pragma unroll
        for (int u = 0; u < UNROLL; ++u) {
            x[u] = L4[i + u * NTHREADS];
            y[u] = Y4[i + u * NTHREADS];
        }
        #pragma unroll
        for (int u = 0; u < UNROLL; ++u) {
            #pragma unroll
            for (int j = 0; j < 4; ++j) {
                float xv = (&x[u].x)[j];
                int   yv = (&y[u].x)[j];
                float p = 1.0f / (1.0f + __expf(-xv));
                float a = ((xv > 0.0f) == (yv != 0)) ? 1.0f : 0.0f; // p>0.5 <=> x>0
                float t = p - a;
                #pragma unroll
                for (int k = 0; k < NBINS; ++k)
                    S[k] += (xv > CE[k]) ? t : 0.0f;
            }
        }
    }

    // remainder float4s (grid-stride, simple)
    for (int r = nMacro * macroStride + blockIdx.x * NTHREADS + tid;
         r < n4; r += NBLOCKS * NTHREADS) {
        float4 x = L4[r];
        int4   y = Y4[r];
        #pragma unroll
        for (int j = 0; j < 4; ++j) {
            float xv = (&x.x)[j];
            int   yv = (&y.x)[j];
            float p = 1.0f / (1.0f + __expf(-xv));
            float a = ((xv > 0.0f) == (yv != 0)) ? 1.0f : 0.0f;
            float t = p - a;
            #pragma unroll
            for (int k = 0; k < NBINS; ++k)
                S[k] += (xv > CE[k]) ? t : 0.0f;
        }
    }

    // scalar tail (n not a multiple of 4) — block 0 only
    if (blockIdx.x == 0) {
        for (int r = (n4 << 2) + tid; r < n; r += NTHREADS) {
            float xv = logits[r];
            int   yv = labels[r];
            float p = 1.0f / (1.0f + __expf(-xv));
            float a = ((xv > 0.0f) == (yv != 0)) ? 1.0f : 0.0f;
            float t = p - a;
            #pragma unroll
            for (int k = 0; k < NBINS; ++k)
                S[k] += (xv > CE[k]) ? t : 0.0f;
        }
    }

    // per-wave butterfly reduce, then cross-wave via tiny LDS
    __shared__ float wavesum[NWAVES][NBINS];
    #pragma unroll
    for (int k = 0; k < NBINS; ++k) {
        float s = S[k];
        #pragma unroll
        for (int m2 = 32; m2 >= 1; m2 >>= 1)
            s += __shfl_xor(s, m2, 64);
        if (lane == 0) wavesum[w][k] = s;
    }
    __syncthreads();

    if (tid < NBINS) {
        float s = 0.0f;
        #pragma unroll
        for (int ww = 0; ww < NWAVES; ++ww) s += wavesum[ww][tid];
        partials[blockIdx.x * NBINS + tid] = s;
    }
}

// Deterministic fixed-order reduction of NBLOCKS x 15 partials, then
// ece = sum_b |S_b - S_{b+1}| / n   (S_15 == 0).
__global__ __launch_bounds__(NTHREADS) void ece_final_kernel(
    const float* __restrict__ partials,
    float* __restrict__ out,
    float inv_n)
{
    __shared__ double red[NBINS];
    const int t = threadIdx.x;
    if (t < 16 * NBINS) {             // 240 threads: 16 per bin
        const int b   = t >> 4;       // 0..14
        const int sub = t & 15;
        double s = 0.0;
        for (int k = sub; k < NBLOCKS; k += 16)
            s += (double)partials[k * NBINS + b];
        s += __shfl_xor(s, 8, 16);
        s += __shfl_xor(s, 4, 16);
        s += __shfl_xor(s, 2, 16);
        s += __shfl_xor(s, 1, 16);
        if (sub == 0) red[b] = s;
    }
    __syncthreads();
    if (t == 0) {
        double e = 0.0;
        #pragma unroll
        for (int b = 0; b < NBINS - 1; ++b)
            e += fabs(red[b] - red[b + 1]);
        e += fabs(red[NBINS - 1]);    // S_15 == 0
        out[0] = (float)(e * (double)inv_n);
    }
}

extern "C" void kernel_launch(void* const* d_in, const int* in_sizes, int n_in,
                              void* d_out, int out_size, void* d_ws, size_t ws_size,
                              hipStream_t stream)
{
    const float* logits = (const float*)d_in[0];
    const int*   labels = (const int*)d_in[1];
    float* out      = (float*)d_out;
    float* partials = (float*)d_ws;   // NBLOCKS * 15 * 4 B = 120 KiB
    const int n = in_sizes[0];

    ece_partial_kernel<<<NBLOCKS, NTHREADS, 0, stream>>>(logits, labels, partials, n);
    ece_final_kernel<<<1, NTHREADS, 0, stream>>>(partials, out, 1.0f / (float)n);
}

// Round 4
// 96.140 us; speedup vs baseline: 1.0143x; 1.0143x over previous
//
#include <hip/hip_runtime.h>

#define NBINS 15
#define NTHREADS 256
#define NWAVES 4
#define NBLOCKS 2048
#define TT (NBLOCKS * NTHREADS)   // 524288 threads
#define ITERS 16                  // fast path: n4 == ITERS * TT

typedef float f32x4 __attribute__((ext_vector_type(4)));
typedef int   i32x4 __attribute__((ext_vector_type(4)));

// Bin edges mapped to logit domain: p > k/15  <=>  x > ln(k/(15-k)).
// CE[0]: p>0 fails only when sigmoid underflows (never for these inputs).
__constant__ float CEc[NBINS] = { -88.72284f,
    -2.63905733f, -1.87180218f, -1.38629436f, -1.01160091f,
    -0.69314718f, -0.40546511f, -0.13353139f,  0.13353139f,
     0.40546511f,  0.69314718f,  1.01160091f,  1.38629436f,
     1.87180218f,  2.63905733f };

// --- forced-MLP pipeline macros (rule #18: sched_barrier after waitcnt) ---
#define ISSUE(s) do {                                                        \
    asm volatile("global_load_dwordx4 %0, %1, off"                           \
                 : "=v"(xb[s]) : "v"(aL) : "memory");                        \
    asm volatile("global_load_dwordx4 %0, %1, off"                           \
                 : "=v"(yb[s]) : "v"(aY) : "memory");                        \
    aL += TT; aY += TT; } while (0)

#define WAITC(N) do {                                                        \
    asm volatile("s_waitcnt vmcnt(" #N ")" ::: "memory");                    \
    __builtin_amdgcn_sched_barrier(0); } while (0)

#define COMPUTE(s) do {                                                      \
    _Pragma("unroll")                                                        \
    for (int j = 0; j < 4; ++j) {                                            \
        float xv = xb[s][j];                                                 \
        int   yv = yb[s][j];                                                 \
        float p = 1.0f / (1.0f + __expf(-xv));                               \
        float a = ((xv > 0.0f) == (yv != 0)) ? 1.0f : 0.0f;                  \
        float t = p - a;                                                     \
        _Pragma("unroll")                                                    \
        for (int k = 0; k < NBINS; ++k)                                      \
            S[k] += (xv > CEc[k]) ? t : 0.0f;                                \
    } } while (0)

#define STEP(s)     do { WAITC(4); COMPUTE(s); ISSUE(s); } while (0)
#define FSTEP(s,N)  do { WAITC(N); COMPUTE(s); } while (0)

// S[k] = sum over elements with p > k/15 of t = p - acc.
// Per-bin (conf - acc) = S[b] - S[b+1]  (S[15] == 0); S[0]'s compare IS the
// reference's validity mask.
__global__ __launch_bounds__(NTHREADS) void ece_partial_kernel(
    const float* __restrict__ logits,
    const int* __restrict__ labels,
    float* __restrict__ partials,
    int n)
{
    float S[NBINS];
    #pragma unroll
    for (int k = 0; k < NBINS; ++k) S[k] = 0.0f;

    const int tid  = threadIdx.x;
    const int lane = tid & 63;
    const int w    = tid >> 6;
    const int n4   = n >> 2;

    if (((n & 3) == 0) && (n4 == ITERS * TT)) {
        // ---- fast path: fully unrolled 16-deep pipeline, 3 pairs in flight
        const f32x4* aL = (const f32x4*)logits + (blockIdx.x * NTHREADS + tid);
        const i32x4* aY = (const i32x4*)labels + (blockIdx.x * NTHREADS + tid);
        f32x4 xb[3];
        i32x4 yb[3];
        ISSUE(0); ISSUE(1); ISSUE(2);            // 6 loads outstanding
        STEP(0); STEP(1); STEP(2);               //  3
        STEP(0); STEP(1); STEP(2);               //  6
        STEP(0); STEP(1); STEP(2);               //  9
        STEP(0); STEP(1); STEP(2);               // 12
        STEP(0);                                 // 13 (16 pairs issued)
        FSTEP(1,4); FSTEP(2,2); FSTEP(0,0);      // drain 4 -> 2 -> 0
    } else {
        // ---- generic fallback (any n)
        const float4* L4 = (const float4*)logits;
        const int4*   Y4 = (const int4*)labels;
        for (int i = blockIdx.x * NTHREADS + tid; i < n4; i += TT) {
            float4 x = L4[i];
            int4   y = Y4[i];
            #pragma unroll
            for (int j = 0; j < 4; ++j) {
                float xv = (&x.x)[j];
                int   yv = (&y.x)[j];
                float p = 1.0f / (1.0f + __expf(-xv));
                float a = ((xv > 0.0f) == (yv != 0)) ? 1.0f : 0.0f;
                float t = p - a;
                #pragma unroll
                for (int k = 0; k < NBINS; ++k)
                    S[k] += (xv > CEc[k]) ? t : 0.0f;
            }
        }
        if (blockIdx.x == 0) {            // scalar tail
            for (int r = (n4 << 2) + tid; r < n; r += NTHREADS) {
                float xv = logits[r];
                int   yv = labels[r];
                float p = 1.0f / (1.0f + __expf(-xv));
                float a = ((xv > 0.0f) == (yv != 0)) ? 1.0f : 0.0f;
                float t = p - a;
                #pragma unroll
                for (int k = 0; k < NBINS; ++k)
                    S[k] += (xv > CEc[k]) ? t : 0.0f;
            }
        }
    }

    // per-wave butterfly reduce, then cross-wave via tiny LDS
    __shared__ float wavesum[NWAVES][NBINS];
    #pragma unroll
    for (int k = 0; k < NBINS; ++k) {
        float s = S[k];
        #pragma unroll
        for (int m2 = 32; m2 >= 1; m2 >>= 1)
            s += __shfl_xor(s, m2, 64);
        if (lane == 0) wavesum[w][k] = s;
    }
    __syncthreads();

    if (tid < NBINS) {
        float s = 0.0f;
        #pragma unroll
        for (int ww = 0; ww < NWAVES; ++ww) s += wavesum[ww][tid];
        partials[blockIdx.x * NBINS + tid] = s;
    }
}

// Deterministic fixed-order reduction of NBLOCKS x 15 partials, then
// ece = sum_b |S_b - S_{b+1}| / n   (S_15 == 0).
__global__ __launch_bounds__(NTHREADS) void ece_final_kernel(
    const float* __restrict__ partials,
    float* __restrict__ out,
    float inv_n)
{
    __shared__ double red[NBINS];
    const int t = threadIdx.x;
    if (t < 16 * NBINS) {             // 240 threads: 16 per bin
        const int b   = t >> 4;
        const int sub = t & 15;
        double s = 0.0;
        for (int k = sub; k < NBLOCKS; k += 16)
            s += (double)partials[k * NBINS + b];
        s += __shfl_xor(s, 8, 16);
        s += __shfl_xor(s, 4, 16);
        s += __shfl_xor(s, 2, 16);
        s += __shfl_xor(s, 1, 16);
        if (sub == 0) red[b] = s;
    }
    __syncthreads();
    if (t == 0) {
        double e = 0.0;
        #pragma unroll
        for (int b = 0; b < NBINS - 1; ++b)
            e += fabs(red[b] - red[b + 1]);
        e += fabs(red[NBINS - 1]);    // S_15 == 0
        out[0] = (float)(e * (double)inv_n);
    }
}

extern "C" void kernel_launch(void* const* d_in, const int* in_sizes, int n_in,
                              void* d_out, int out_size, void* d_ws, size_t ws_size,
                              hipStream_t stream)
{
    const float* logits = (const float*)d_in[0];
    const int*   labels = (const int*)d_in[1];
    float* out      = (float*)d_out;
    float* partials = (float*)d_ws;   // NBLOCKS * 15 * 4 B = 120 KiB
    const int n = in_sizes[0];

    ece_partial_kernel<<<NBLOCKS, NTHREADS, 0, stream>>>(logits, labels, partials, n);
    ece_final_kernel<<<1, NTHREADS, 0, stream>>>(partials, out, 1.0f / (float)n);
}